// Round 6
// baseline (289.065 us; speedup 1.0000x reference)
//
#include <hip/hip_runtime.h>

#define Hh 64
#define Ww 64
#define Cc 512
#define Bb 16
#define NTOK (1 + Hh * Ww)   // 4097
#define TW 8                 // output pixels per thread along w
#define NROWS 22             // block's unique input rows: 16 outputs + 6 halo

typedef float v2f __attribute__((ext_vector_type(2)));
typedef const float __attribute__((address_space(1))) gcf;   // global
typedef float       __attribute__((address_space(3))) lsf;   // LDS

// ---------------------------------------------------------------------------
// Prep kernel (unchanged): combine w7 + padded w5 + padded w3 + identity into
// one effective 7x7 kernel per channel, stored TRANSPOSED [tap][channel].
// Combine biases, copy cls tokens through.
// ---------------------------------------------------------------------------
__global__ void ppeg_prep(const float* __restrict__ w7, const float* __restrict__ b7,
                          const float* __restrict__ w5, const float* __restrict__ b5,
                          const float* __restrict__ w3, const float* __restrict__ b3,
                          const float* __restrict__ x, float* __restrict__ wt,
                          float* __restrict__ beff, float* __restrict__ out) {
    int idx = blockIdx.x * blockDim.x + threadIdx.x;
    if (idx < Cc * 49) {
        int c = idx / 49, t = idx % 49;
        int r = t / 7, s = t % 7;
        float v = w7[idx];
        if (r >= 1 && r <= 5 && s >= 1 && s <= 5) v += w5[c * 25 + (r - 1) * 5 + (s - 1)];
        if (r >= 2 && r <= 4 && s >= 2 && s <= 4) v += w3[c * 9 + (r - 2) * 3 + (s - 2)];
        if (t == 24) v += 1.0f;               // identity (center tap)
        wt[t * Cc + c] = v;                   // transposed store
    }
    if (idx < Cc) beff[idx] = b7[idx] + b5[idx] + b3[idx];
    if (idx < Bb * Cc) {
        int b = idx / Cc, c = idx % Cc;
        size_t o = (size_t)b * NTOK * Cc + c;
        out[o] = x[o];                        // cls token pass-through
    }
}

// ---------------------------------------------------------------------------
// Conv kernel v7: global_load_lds double-buffered ROW STAGING.
//
// v6 post-mortem: XCD swizzle confirmed (FETCH = 134 MB compulsory minimum)
// but time barely moved (104 us): VALUBusy 26% with traffic optimal means
// the waves serialize {14-load burst -> drain -> 1100cy FMA}. The 64-VGPR
// allocation (acc lives in AGPRs) leaves no room to hoist the next row's
// 28-reg window over the current row's FMAs, and 2 rounds of allocator
// fighting (R2/R3) showed attributes can't fix it. So: move the in-flight
// data OUT of registers.
//
//  - Per block (16h x 8w x 128ch): 22 unique input rows. Each row staged
//    ONCE into LDS via 7x global_load_lds(width=16) (1024 B/inst, 2 pixels),
//    split across the 4 waves (<=2 insts each). This also removes the 1.8x
//    intra-block halo duplication (4 ty-strips previously re-read
//    overlapping rows: 40 raw row-reads vs 22 unique).
//  - Double-buffered: compute(m) reads rbuf[m&1]; the __syncthreads() after
//    it drains this wave's outstanding stage (vmcnt) and fences readers;
//    stage(m+2) -> rbuf[m&1] issues right after the barrier and flies under
//    compute(m+1)'s ~450-900 cy of FMA. One barrier per row.
//  - Output rows interleaved ol = 4*o + ty: a staged row feeds 7 consecutive
//    output rows = (2,2,2,1) split across waves -> balanced barriers (the
//    naive ty-strip split would be 3x imbalanced).
//  - Window reads are ds_read_b64 stride-8B (2-way bank alias = free, m136).
//  - w-edge zeros applied in-register after the LDS read (staging clamps
//    out-of-range pixel addresses; clamped slots are masked, never used).
//  - LDS = 25088 (taps) + 14336 (2x7168 rows) = 39424 B -> 4 blocks/CU.
//  - Keep: chunked XCD swizzle (proven: FETCH 243->134 MB), nontemporal
//    stores, 256-thread blocks (the allocator-sane workgroup shape).
// ---------------------------------------------------------------------------
__global__ __launch_bounds__(256, 2)
void ppeg_conv(const float* __restrict__ x, const float* __restrict__ wt,
               const float* __restrict__ beff, float* __restrict__ out) {
    const int tx = threadIdx.x;        // lane 0..63
    const int ty = threadIdx.y;        // wave 0..3

    // --- chunked XCD swizzle (XCD = linear id % 8, x fastest; bijective) ----
    const int L     = blockIdx.x + 32 * (blockIdx.y + 4 * blockIdx.z); // 0..2047
    const int g_lin = (L & 7) * 256 + (L >> 3);
    const int sp    = g_lin & 31;      // spatial block 0..31 within group
    const int g     = g_lin >> 5;      // 0..63 : (cblk, b) group
    const int cb    = (g & 3) * 128;
    const int b     = g >> 2;
    // ------------------------------------------------------------------------

    const int wblk  = sp & 7;
    const int hblk  = sp >> 3;
    const int wbase = wblk * TW;
    const int ohb   = hblk * 16;       // block's first output row

    __shared__ float taps[49][128];
    __shared__ float rbuf[2][14][128]; // [buf][pixel][channel]

    // Stage the block's 49x128 tap slab into LDS (once), coalesced.
    const int tid = ty * 64 + tx;
    for (int idx = tid; idx < 49 * 128; idx += 256) {
        taps[idx >> 7][idx & 127] = wt[(idx >> 7) * Cc + cb + (idx & 127)];
    }

    // Async row staging: row m (local) -> rbuf[bufi]. 7 insts x 1024 B;
    // wave ty issues insts {ty, ty+4}. Global src per-lane (2 pixels per
    // inst: lanes 0..31 pixel 2t, lanes 32..63 pixel 2t+1; 16 B/lane of the
    // 512 B channel slab). LDS dest wave-uniform base + lane*16 (linear).
    auto stage = [&](int m, int bufi) {
        const int ir = ohb + m - 3;            // block-uniform
        if (ir < 0 || ir >= Hh) return;
#pragma unroll
        for (int tt = 0; tt < 2; ++tt) {
            const int t = ty + 4 * tt;
            if (t < 7) {
                int pc = wbase - 3 + 2 * t + (tx >> 5);
                pc = pc < 0 ? 0 : (pc > Ww - 1 ? Ww - 1 : pc);   // clamp (masked later)
                const float* gp = x + ((size_t)b * NTOK + 1 + (size_t)ir * Ww + pc) * Cc
                                    + cb + (tx & 31) * 4;
                __builtin_amdgcn_global_load_lds((gcf*)gp, (lsf*)&rbuf[bufi][2 * t][0],
                                                 16, 0, 0);
            }
        }
    };

    stage(0, 0);
    stage(1, 1);
    __syncthreads();                    // drains vmcnt: rows 0,1 + taps ready

    const int c0 = cb + 2 * tx;
    const v2f bias = *(const v2f*)&beff[c0];
    v2f acc[4][TW];
#pragma unroll
    for (int o = 0; o < 4; ++o)
#pragma unroll
        for (int j = 0; j < TW; ++j) acc[o][j] = bias;

    const bool interior = (wblk != 0) && (wblk != 7);

    // Lockstep over the block's 22 input rows. Row m feeds output rows
    // ol in [m-6, m]; this thread owns ol = 4*o + ty (o = 0..3).
#pragma unroll
    for (int m = 0; m < NROWS; ++m) {
        const int ir = ohb + m - 3;
        if (ir >= 0 && ir < Hh) {              // block-uniform
            const int d = m - ty;              // r = d - 4*o, valid iff 0<=r<=6
            if (d >= 0 && d <= 18) {           // wave-uniform: any o active
                v2f v[14];
#pragma unroll
                for (int j = 0; j < 14; ++j)
                    v[j] = *(const v2f*)&rbuf[m & 1][j][2 * tx];
                if (!interior) {
#pragma unroll
                    for (int j = 0; j < 14; ++j) {
                        const int wc = wbase + j - 3;
                        if (wc < 0 || wc >= Ww) { v[j].x = 0.0f; v[j].y = 0.0f; }
                    }
                }
#pragma unroll
                for (int o = 0; o < 4; ++o) {
                    const int r = d - 4 * o;   // wave-uniform runtime tap row
                    if (r >= 0 && r <= 6) {
#pragma unroll
                        for (int s = 0; s < 7; ++s) {
                            const v2f tp = *(const v2f*)&taps[r * 7 + s][2 * tx];
#pragma unroll
                            for (int j = 0; j < TW; ++j) {
                                acc[o][j].x = fmaf(tp.x, v[j + s].x, acc[o][j].x);
                                acc[o][j].y = fmaf(tp.y, v[j + s].y, acc[o][j].y);
                            }
                        }
                    }
                }
            }
        }
        __syncthreads();                       // readers done + stage(m+1) landed
        if (m + 2 < NROWS) stage(m + 2, m & 1);
    }

#pragma unroll
    for (int o = 0; o < 4; ++o) {
        const int ohr = ohb + 4 * o + ty;
        float* orow = out + ((size_t)b * NTOK + 1 + (size_t)ohr * Ww + wbase) * Cc + c0;
#pragma unroll
        for (int j = 0; j < TW; ++j)
            __builtin_nontemporal_store(acc[o][j], (v2f*)(orow + (size_t)j * Cc));
    }
}

extern "C" void kernel_launch(void* const* d_in, const int* in_sizes, int n_in,
                              void* d_out, int out_size, void* d_ws, size_t ws_size,
                              hipStream_t stream) {
    const float* x  = (const float*)d_in[0];
    const float* w7 = (const float*)d_in[1];
    const float* b7 = (const float*)d_in[2];
    const float* w5 = (const float*)d_in[3];
    const float* b5 = (const float*)d_in[4];
    const float* w3 = (const float*)d_in[5];
    const float* b3 = (const float*)d_in[6];
    float* out = (float*)d_out;

    float* wt   = (float*)d_ws;          // 49*Cc floats, transposed [tap][channel]
    float* beff = wt + 49 * Cc;          // Cc floats

    ppeg_prep<<<(Cc * 49 + 255) / 256, 256, 0, stream>>>(w7, b7, w5, b5, w3, b3,
                                                         x, wt, beff, out);

    // (4 hblk x 8 wblk) x 4 cblk x 16 b = 2048 blocks of 256 threads.
    dim3 grid(32, Cc / 128, Bb);
    dim3 block(64, 4);
    ppeg_conv<<<grid, block, 0, stream>>>(x, wt, beff, out);
}

// Round 7
// 286.773 us; speedup vs baseline: 1.0080x; 1.0080x over previous
//
#include <hip/hip_runtime.h>

#define Hh 64
#define Ww 64
#define Cc 512
#define Bb 16
#define NTOK (1 + Hh * Ww)   // 4097
#define TW 8                 // output pixels per thread along w
#define NROWS 22             // block's unique input rows: 16 outputs + 6 halo
#define DBUF 3               // row-buffer ring depth (prefetch distance 2)

typedef float v2f __attribute__((ext_vector_type(2)));
typedef const float __attribute__((address_space(1))) gcf;   // global
typedef float       __attribute__((address_space(3))) lsf;   // LDS

// ---------------------------------------------------------------------------
// Prep kernel (unchanged): combine w7 + padded w5 + padded w3 + identity into
// one effective 7x7 kernel per channel, stored TRANSPOSED [tap][channel].
// Combine biases, copy cls tokens through.
// ---------------------------------------------------------------------------
__global__ void ppeg_prep(const float* __restrict__ w7, const float* __restrict__ b7,
                          const float* __restrict__ w5, const float* __restrict__ b5,
                          const float* __restrict__ w3, const float* __restrict__ b3,
                          const float* __restrict__ x, float* __restrict__ wt,
                          float* __restrict__ beff, float* __restrict__ out) {
    int idx = blockIdx.x * blockDim.x + threadIdx.x;
    if (idx < Cc * 49) {
        int c = idx / 49, t = idx % 49;
        int r = t / 7, s = t % 7;
        float v = w7[idx];
        if (r >= 1 && r <= 5 && s >= 1 && s <= 5) v += w5[c * 25 + (r - 1) * 5 + (s - 1)];
        if (r >= 2 && r <= 4 && s >= 2 && s <= 4) v += w3[c * 9 + (r - 2) * 3 + (s - 2)];
        if (t == 24) v += 1.0f;               // identity (center tap)
        wt[t * Cc + c] = v;                   // transposed store
    }
    if (idx < Cc) beff[idx] = b7[idx] + b5[idx] + b3[idx];
    if (idx < Bb * Cc) {
        int b = idx / Cc, c = idx % Cc;
        size_t o = (size_t)b * NTOK * Cc + c;
        out[o] = x[o];                        // cls token pass-through
    }
}

// ---------------------------------------------------------------------------
// Conv kernel v8 = v7 structure with the sync discipline replaced by the
// HW-verified counted-vmcnt pipeline (T3/T4, m194-m199 pattern).
//
// v7 post-mortem: __syncthreads() = s_waitcnt vmcnt(0) lgkmcnt(0) +
// s_barrier. Every one of the 22 per-row barriers drained ALL outstanding
// DMA, so stage(m+2) had to fully land before barrier m+1 -> 22 serialized
// latency exposures per block (VALUBusy stuck at 28%, 127 us). The staging
// structure was right; the barrier semantics killed it.
//
// v8 sync discipline (never drain vmcnt in the loop):
//  - Ring of 3 row buffers: stage(m+2) issued in iteration m, consumed in
//    iteration m+2 -> ~2 row-times (~1100 cy) of slack > HBM latency.
//  - UNIFORM staging ledger: every wave issues exactly 2 global_load_lds
//    per row (8 insts cover 16 pixels; pixels 14-15 are clamped garbage,
//    never read). At iteration m each wave's outstanding = rows {m, m+1}
//    = 4 insts, so `s_waitcnt vmcnt(2)` == "my share of row m landed";
//    then raw s_barrier -> ALL waves' shares of row m landed. vmcnt(0)
//    only at the final row. Out-of-range rows stage clamped row addresses
//    (uniform count preserved); compute skips them.
//  - sched_barrier(0) pins each iteration's region (rule #18 insurance);
//    "memory" clobber on the waitcnt asm keeps rbuf ds_reads from hoisting
//    above it. In-loop global traffic is DMA-only (taps/bias preloaded,
//    stores after loop), so the vmcnt ledger is exact.
//  - LDS = 25088 (taps) + 24576 (ring) = 49664 B -> 3 blocks/CU.
//  - Keep: chunked XCD swizzle (proven: FETCH -> compulsory minimum),
//    interleaved output rows ol = 4*o+ty (balanced per-row wave load),
//    nontemporal stores, 256-thread blocks.
// ---------------------------------------------------------------------------
__global__ __launch_bounds__(256, 2)
void ppeg_conv(const float* __restrict__ x, const float* __restrict__ wt,
               const float* __restrict__ beff, float* __restrict__ out) {
    const int tx = threadIdx.x;        // lane 0..63
    const int ty = threadIdx.y;        // wave 0..3

    // --- chunked XCD swizzle (XCD = linear id % 8, x fastest; bijective) ----
    const int L     = blockIdx.x + 32 * (blockIdx.y + 4 * blockIdx.z); // 0..2047
    const int g_lin = (L & 7) * 256 + (L >> 3);
    const int sp    = g_lin & 31;      // spatial block 0..31 within group
    const int g     = g_lin >> 5;      // 0..63 : (cblk, b) group
    const int cb    = (g & 3) * 128;
    const int b     = g >> 2;
    // ------------------------------------------------------------------------

    const int wblk  = sp & 7;
    const int hblk  = sp >> 3;
    const int wbase = wblk * TW;
    const int ohb   = hblk * 16;       // block's first output row

    __shared__ float taps[49][128];
    __shared__ float rbuf[DBUF][16][128];   // [ring][pixel][channel]

    // Stage the block's 49x128 tap slab into LDS (once), coalesced.
    const int tid = ty * 64 + tx;
    for (int idx = tid; idx < 49 * 128; idx += 256) {
        taps[idx >> 7][idx & 127] = wt[(idx >> 7) * Cc + cb + (idx & 127)];
    }

    // Bias + acc init BEFORE the pipeline starts: its global load drains at
    // the initial __syncthreads, keeping the in-loop vmcnt ledger DMA-only.
    const int c0 = cb + 2 * tx;
    const v2f bias = *(const v2f*)&beff[c0];
    v2f acc[4][TW];
#pragma unroll
    for (int o = 0; o < 4; ++o)
#pragma unroll
        for (int j = 0; j < TW; ++j) acc[o][j] = bias;

    // Row staging: exactly 2 DMA insts per wave per row (uniform ledger).
    // Inst t (= 2*ty + tt) covers pixels (2t, 2t+1): lanes 0..31 -> pixel 2t,
    // lanes 32..63 -> pixel 2t+1; 16 B/lane of the 512 B channel slab.
    // LDS dest wave-uniform base + lane*16 (linear, as DMA requires).
    auto stage = [&](int m) {
        int ir = ohb + m - 3;
        ir = ir < 0 ? 0 : (ir > Hh - 1 ? Hh - 1 : ir);       // clamp (never read if OOR)
        const int bufi = m % DBUF;                           // unroll-time constant
#pragma unroll
        for (int tt = 0; tt < 2; ++tt) {
            const int t = 2 * ty + tt;                       // 0..7
            int pc = wbase - 3 + 2 * t + (tx >> 5);
            pc = pc < 0 ? 0 : (pc > Ww - 1 ? Ww - 1 : pc);   // clamp (masked later)
            const float* gp = x + ((size_t)b * NTOK + 1 + (size_t)ir * Ww + pc) * Cc
                                + cb + (tx & 31) * 4;
            __builtin_amdgcn_global_load_lds((gcf*)gp, (lsf*)&rbuf[bufi][2 * t][0],
                                             16, 0, 0);
        }
    };

    __syncthreads();                   // taps + bias drained; vmcnt ledger = 0
    stage(0);                          // outstanding: row 0 (2 insts)
    stage(1);                          //            + row 1 (2 insts) = 4

    const bool interior = (wblk != 0) && (wblk != 7);

    // Lockstep over the block's 22 input rows; one raw barrier per row.
#pragma unroll
    for (int m = 0; m < NROWS; ++m) {
        // My share of row m landed (outstanding <= rows m+1.. = 2 insts).
        if (m == NROWS - 1) asm volatile("s_waitcnt vmcnt(0)" ::: "memory");
        else                asm volatile("s_waitcnt vmcnt(2)" ::: "memory");
        __builtin_amdgcn_sched_barrier(0);
        __builtin_amdgcn_s_barrier();  // all waves' shares of row m landed;
                                       // also: all waves done reading row m-1
        if (m + 2 < NROWS) stage(m + 2);   // overwrites buf of row m-1 (free)

        const int ir = ohb + m - 3;
        if (ir >= 0 && ir < Hh) {              // block-uniform
            const int d = m - ty;              // r = d - 4*o, valid iff 0<=r<=6
            if (d >= 0 && d <= 18) {           // wave-uniform: any o active
                v2f v[14];
#pragma unroll
                for (int j = 0; j < 14; ++j)
                    v[j] = *(const v2f*)&rbuf[m % DBUF][j][2 * tx];
                if (!interior) {
#pragma unroll
                    for (int j = 0; j < 14; ++j) {
                        const int wc = wbase + j - 3;
                        if (wc < 0 || wc >= Ww) { v[j].x = 0.0f; v[j].y = 0.0f; }
                    }
                }
#pragma unroll
                for (int o = 0; o < 4; ++o) {
                    const int r = d - 4 * o;   // wave-uniform runtime tap row
                    if (r >= 0 && r <= 6) {
#pragma unroll
                        for (int s = 0; s < 7; ++s) {
                            const v2f tp = *(const v2f*)&taps[r * 7 + s][2 * tx];
#pragma unroll
                            for (int j = 0; j < TW; ++j) {
                                acc[o][j].x = fmaf(tp.x, v[j + s].x, acc[o][j].x);
                                acc[o][j].y = fmaf(tp.y, v[j + s].y, acc[o][j].y);
                            }
                        }
                    }
                }
            }
        }
    }

#pragma unroll
    for (int o = 0; o < 4; ++o) {
        const int ohr = ohb + 4 * o + ty;
        float* orow = out + ((size_t)b * NTOK + 1 + (size_t)ohr * Ww + wbase) * Cc + c0;
#pragma unroll
        for (int j = 0; j < TW; ++j)
            __builtin_nontemporal_store(acc[o][j], (v2f*)(orow + (size_t)j * Cc));
    }
}

extern "C" void kernel_launch(void* const* d_in, const int* in_sizes, int n_in,
                              void* d_out, int out_size, void* d_ws, size_t ws_size,
                              hipStream_t stream) {
    const float* x  = (const float*)d_in[0];
    const float* w7 = (const float*)d_in[1];
    const float* b7 = (const float*)d_in[2];
    const float* w5 = (const float*)d_in[3];
    const float* b5 = (const float*)d_in[4];
    const float* w3 = (const float*)d_in[5];
    const float* b3 = (const float*)d_in[6];
    float* out = (float*)d_out;

    float* wt   = (float*)d_ws;          // 49*Cc floats, transposed [tap][channel]
    float* beff = wt + 49 * Cc;          // Cc floats

    ppeg_prep<<<(Cc * 49 + 255) / 256, 256, 0, stream>>>(w7, b7, w5, b5, w3, b3,
                                                         x, wt, beff, out);

    // (4 hblk x 8 wblk) x 4 cblk x 16 b = 2048 blocks of 256 threads.
    dim3 grid(32, Cc / 128, Bb);
    dim3 block(64, 4);
    ppeg_conv<<<grid, block, 0, stream>>>(x, wt, beff, out);
}